// Round 3
// baseline (661.381 us; speedup 1.0000x reference)
//
#include <hip/hip_runtime.h>
#include <stdint.h>

#define NN   4096
#define KK   32
#define HID  128
#define BLK  128

typedef unsigned short bf16_t;

__device__ __forceinline__ float bf2f(bf16_t u) {
    return __uint_as_float(((uint32_t)u) << 16);
}
__device__ __forceinline__ bf16_t f2bf(float f) {
    uint32_t u = __float_as_uint(f);
    u = u + 0x7fffu + ((u >> 16) & 1u);   // round-to-nearest-even
    return (bf16_t)(u >> 16);
}
__device__ __forceinline__ float2 bfp2(uint32_t w) {  // packed bf16x2 -> 2 floats
    return make_float2(__uint_as_float(w << 16), __uint_as_float(w & 0xffff0000u));
}
__device__ __forceinline__ float siluf(float x) {
    return x / (1.0f + __expf(-x));
}

// runtime-dtype load: F32 path reads float*, else bf16*
template<bool F32>
__device__ __forceinline__ float ld(const void* p, int i) {
    return F32 ? ((const float*)p)[i] : bf2f(((const bf16_t*)p)[i]);
}

struct __align__(16) Smem {
    float dist[NN];            // 16 KB; aliased as per-wave h1 storage in MLP phase
    uint32_t w2l[HID * 64];    // 32 KB; W2 bf16x2 packed, 16B chunks XOR-swizzled
    unsigned long long redk[2];
    int recvs[KK];
    float wtr[2][3];
};

template<bool F32>
__device__ __forceinline__ void egnn_body(
    Smem& sm,
    const void* __restrict__ pos, const void* __restrict__ tptr,
    const void* __restrict__ W1,  const void* __restrict__ b1,
    const void* __restrict__ g1,  const void* __restrict__ W2,
    const void* __restrict__ b2,  const void* __restrict__ g2,
    const void* __restrict__ W3,  const void* __restrict__ b3,
    float* __restrict__ out)
{
    const int tid  = threadIdx.x;
    const int lane = tid & 63;
    const int wid  = tid >> 6;
    const int i    = blockIdx.x;

    // per-lane neuron constants: neurons n0 = lane, n1 = lane + 64
    const int n0 = lane, n1 = lane + 64;
    const float ts   = ld<F32>(tptr, 0);
    const float w1a0 = ld<F32>(W1, 2*n0), w1b0 = ld<F32>(W1, 2*n0+1);
    const float w1a1 = ld<F32>(W1, 2*n1), w1b1 = ld<F32>(W1, 2*n1+1);
    const float tc0  = ts * w1b0 + ld<F32>(b1, n0);
    const float tc1  = ts * w1b1 + ld<F32>(b1, n1);
    const float g10  = ld<F32>(g1, n0), g11 = ld<F32>(g1, n1);
    const float b20  = ld<F32>(b2, n0), b21 = ld<F32>(b2, n1);
    const float g20  = ld<F32>(g2, n0), g21 = ld<F32>(g2, n1);
    const float w30  = ld<F32>(W3, n0), w31 = ld<F32>(W3, n1);
    const float b3s  = ld<F32>(b3, 0);

    // ---- stage W2 into LDS (bf16 packed regardless of src dtype; swizzled) ----
    for (int idx = tid; idx < HID * 16; idx += BLK) {
        int row = idx >> 4, c = idx & 15;
        uint4 pk;
        if (F32) {
            const float* src = (const float*)W2 + row * HID + c * 8;
            float4 lo = *(const float4*)src;
            float4 hi = *(const float4*)(src + 4);
            pk.x = (uint32_t)f2bf(lo.x) | ((uint32_t)f2bf(lo.y) << 16);
            pk.y = (uint32_t)f2bf(lo.z) | ((uint32_t)f2bf(lo.w) << 16);
            pk.z = (uint32_t)f2bf(hi.x) | ((uint32_t)f2bf(hi.y) << 16);
            pk.w = (uint32_t)f2bf(hi.z) | ((uint32_t)f2bf(hi.w) << 16);
        } else {
            pk = ((const uint4*)W2)[idx];
        }
        *((uint4*)&sm.w2l[row * 64 + 4 * (c ^ (row & 15))]) = pk;
    }

    const float px = ld<F32>(pos, 3*i), py = ld<F32>(pos, 3*i+1), pz = ld<F32>(pos, 3*i+2);

    // ---- pairwise distances (exact fp32 mul/add chain: match np rounding) ----
    for (int j = tid; j < NN; j += BLK) {
        float dx = px - ld<F32>(pos, 3*j);
        float dy = py - ld<F32>(pos, 3*j+1);
        float dz = pz - ld<F32>(pos, 3*j+2);
        float d  = __fadd_rn(__fadd_rn(__fmul_rn(dx,dx), __fmul_rn(dy,dy)), __fmul_rn(dz,dz));
        sm.dist[j] = (j == i) ? __uint_as_float(0x7f800000u) : d;
    }
    __syncthreads();

    // ---- 32x argmin; key = (distbits<<12)|j gives jax's lower-index tie-break ----
    for (int it = 0; it < KK; ++it) {
        unsigned long long best = ~0ull;
        for (int j = tid; j < NN; j += BLK) {
            unsigned long long key =
                (((unsigned long long)__float_as_uint(sm.dist[j])) << 12) | (unsigned)j;
            best = best < key ? best : key;
        }
        #pragma unroll
        for (int m = 32; m >= 1; m >>= 1) {
            unsigned long long o = __shfl_xor(best, m, 64);
            best = best < o ? best : o;
        }
        if (lane == 0) sm.redk[wid] = best;
        __syncthreads();
        if (tid == 0) {
            unsigned long long b = sm.redk[0] < sm.redk[1] ? sm.redk[0] : sm.redk[1];
            int idx = (int)(b & 0xfffull);
            sm.recvs[it] = idx;
            sm.dist[idx] = __uint_as_float(0x7f800000u);
        }
        __syncthreads();
    }

    // ---- edge MLP: wave w handles edges [g*16 + w*8, +8); all 128 neurons/wave ----
    float* h1s = sm.dist + wid * (8 * HID);   // alias; kNN done with dist
    float a3x = 0.f, a3y = 0.f, a3z = 0.f;
    const int sw = lane & 15;

    for (int g = 0; g < 2; ++g) {
        const int eb = g * 16 + wid * 8;
        float cdx[8], cdy[8], cdz[8], p0v[8], p1v[8], sq[8];
        #pragma unroll
        for (int e = 0; e < 8; ++e) {
            int r = sm.recvs[eb + e];
            float dx = px - ld<F32>(pos, 3*r);
            float dy = py - ld<F32>(pos, 3*r+1);
            float dz = pz - ld<F32>(pos, 3*r+2);
            cdx[e] = dx; cdy[e] = dy; cdz[e] = dz;
            float rad = __fadd_rn(__fadd_rn(__fmul_rn(dx,dx), __fmul_rn(dy,dy)), __fmul_rn(dz,dz));
            float p0 = rad * w1a0 + tc0;
            float p1 = rad * w1a1 + tc1;
            p0v[e] = p0; p1v[e] = p1;
            sq[e] = p0*p0 + p1*p1;
        }
        #pragma unroll
        for (int m = 32; m >= 1; m >>= 1) {
            #pragma unroll
            for (int e = 0; e < 8; ++e) sq[e] += __shfl_xor(sq[e], m, 64);
        }
        __syncthreads();   // previous phase's reads of this LDS range are done
        #pragma unroll
        for (int e = 0; e < 8; ++e) {
            float rn = rsqrtf(sq[e] * (1.0f/HID) + 1e-5f);
            h1s[e*HID + n0] = siluf(p0v[e] * rn * g10);
            h1s[e*HID + n1] = siluf(p1v[e] * rn * g11);
        }
        __syncthreads();   // h1s visible; keeps both waves in phase

        float acc0[8], acc1[8];
        #pragma unroll
        for (int e = 0; e < 8; ++e) { acc0[e] = b20; acc1[e] = b21; }

        for (int c = 0; c < 16; ++c) {
            uint4 wa = *((const uint4*)&sm.w2l[n0*64 + 4*(c ^ sw)]);
            uint4 wb = *((const uint4*)&sm.w2l[n1*64 + 4*(c ^ sw)]);
            float2 a0 = bfp2(wa.x), a1 = bfp2(wa.y), a2 = bfp2(wa.z), a3 = bfp2(wa.w);
            float2 q0 = bfp2(wb.x), q1 = bfp2(wb.y), q2 = bfp2(wb.z), q3 = bfp2(wb.w);
            #pragma unroll
            for (int e = 0; e < 8; ++e) {
                const float4 ha = *((const float4*)&h1s[e*HID + c*8]);
                const float4 hb = *((const float4*)&h1s[e*HID + c*8 + 4]);
                acc0[e] += a0.x*ha.x + a0.y*ha.y + a1.x*ha.z + a1.y*ha.w
                         + a2.x*hb.x + a2.y*hb.y + a3.x*hb.z + a3.y*hb.w;
                acc1[e] += q0.x*ha.x + q0.y*ha.y + q1.x*ha.z + q1.y*ha.w
                         + q2.x*hb.x + q2.y*hb.y + q3.x*hb.z + q3.y*hb.w;
            }
        }

        #pragma unroll
        for (int e = 0; e < 8; ++e) sq[e] = acc0[e]*acc0[e] + acc1[e]*acc1[e];
        #pragma unroll
        for (int m = 32; m >= 1; m >>= 1) {
            #pragma unroll
            for (int e = 0; e < 8; ++e) sq[e] += __shfl_xor(sq[e], m, 64);
        }
        float sv[8];
        #pragma unroll
        for (int e = 0; e < 8; ++e) {
            float rn  = rsqrtf(sq[e] * (1.0f/HID) + 1e-5f);
            float h20 = siluf(acc0[e] * rn * g20);
            float h21 = siluf(acc1[e] * rn * g21);
            sv[e] = h20 * w30 + h21 * w31;
        }
        #pragma unroll
        for (int m = 32; m >= 1; m >>= 1) {
            #pragma unroll
            for (int e = 0; e < 8; ++e) sv[e] += __shfl_xor(sv[e], m, 64);
        }
        #pragma unroll
        for (int e = 0; e < 8; ++e) {
            float s = sv[e] + b3s;
            a3x += cdx[e]*s; a3y += cdy[e]*s; a3z += cdz[e]*s;
        }
    }

    if (lane == 0) { sm.wtr[wid][0] = a3x; sm.wtr[wid][1] = a3y; sm.wtr[wid][2] = a3z; }
    __syncthreads();
    if (tid < 3) {
        float base = ld<F32>(pos, 3*i + tid);
        float v = base + (sm.wtr[0][tid] + sm.wtr[1][tid]) * (1.0f/KK);
        out[3*i + tid] = v;   // fp32 output
    }
}

__global__ __launch_bounds__(BLK) void egnn_fused(
    const void* __restrict__ pos, const void* __restrict__ tptr,
    const void* __restrict__ W1,  const void* __restrict__ b1,
    const void* __restrict__ g1,  const void* __restrict__ W2,
    const void* __restrict__ b2,  const void* __restrict__ g2,
    const void* __restrict__ W3,  const void* __restrict__ b3,
    float* __restrict__ out)
{
    __shared__ Smem sm;
    // dtype sniff: g1 is all-ones. fp32 ones -> dword 0x3F800000 (low16==0);
    // bf16 ones -> dword 0x3F803F80 (low16!=0). Block-uniform branch.
    const bool f32in = ((((const uint32_t*)g1)[0] & 0xFFFFu) == 0u);
    if (f32in)
        egnn_body<true >(sm, pos, tptr, W1, b1, g1, W2, b2, g2, W3, b3, out);
    else
        egnn_body<false>(sm, pos, tptr, W1, b1, g1, W2, b2, g2, W3, b3, out);
}

extern "C" void kernel_launch(void* const* d_in, const int* in_sizes, int n_in,
                              void* d_out, int out_size, void* d_ws, size_t ws_size,
                              hipStream_t stream) {
    (void)in_sizes; (void)n_in; (void)out_size; (void)d_ws; (void)ws_size;
    egnn_fused<<<NN, BLK, 0, stream>>>(
        d_in[0], d_in[1], d_in[2], d_in[3], d_in[4],
        d_in[5], d_in[6], d_in[7], d_in[8], d_in[9],
        (float*)d_out);
}

// Round 4
// 197.577 us; speedup vs baseline: 3.3475x; 3.3475x over previous
//
#include <hip/hip_runtime.h>
#include <stdint.h>

#define NN   4096
#define KK   32
#define HID  128
#define BLK  256
#define CAP  256

typedef unsigned short bf16_t;

__device__ __forceinline__ bf16_t f2bf(float f) {
    uint32_t u = __float_as_uint(f);
    u = u + 0x7fffu + ((u >> 16) & 1u);   // round-to-nearest-even
    return (bf16_t)(u >> 16);
}
__device__ __forceinline__ float2 bfp2(uint32_t w) {  // packed bf16x2 -> 2 floats
    return make_float2(__uint_as_float(w << 16), __uint_as_float(w & 0xffff0000u));
}
__device__ __forceinline__ float siluf(float x) {
    return x / (1.0f + __expf(-x));
}

struct __align__(16) Smem {
    float dist[NN];            // 16 KB; aliased as h1 storage (32 edges x 128) in MLP
    uint32_t w2l[HID * 64];    // 32 KB; W2 bf16x2 packed, 16B chunks XOR-swizzled
    union {                    // phase-disjoint: hist (select) then cand (compaction)
        uint32_t hist[1024];
        unsigned long long cand[CAP];
    } u;
    int recvs[KK];
    float wtr[4][3];
    int waveTot[4];
    unsigned long long redk[4];
    int pivotB;
    int cnt;
};

__global__ __launch_bounds__(BLK) void egnn_fused(
    const float* __restrict__ pos, const float* __restrict__ tptr,
    const float* __restrict__ W1,  const float* __restrict__ b1,
    const float* __restrict__ g1,  const float* __restrict__ W2,
    const float* __restrict__ b2,  const float* __restrict__ g2,
    const float* __restrict__ W3,  const float* __restrict__ b3,
    float* __restrict__ out)
{
    __shared__ Smem sm;
    const int tid  = threadIdx.x;
    const int lane = tid & 63;
    const int wid  = tid >> 6;
    const int i    = blockIdx.x;

    // per-lane neuron constants: neurons n0 = lane, n1 = lane + 64 (same all waves)
    const int n0 = lane, n1 = lane + 64;
    const float ts   = tptr[0];
    const float w1a0 = W1[2*n0], w1b0 = W1[2*n0+1];
    const float w1a1 = W1[2*n1], w1b1 = W1[2*n1+1];
    const float tc0  = ts * w1b0 + b1[n0];
    const float tc1  = ts * w1b1 + b1[n1];
    const float g10  = g1[n0], g11 = g1[n1];
    const float b20  = b2[n0], b21 = b2[n1];
    const float g20  = g2[n0], g21 = g2[n1];
    const float w30  = W3[n0], w31 = W3[n1];
    const float b3s  = b3[0];

    // ---- stage W2 into LDS (bf16 packed, 16B chunks XOR-swizzled by row&15) ----
    for (int idx = tid; idx < HID * 16; idx += BLK) {
        int row = idx >> 4, c = idx & 15;
        const float* src = W2 + row * HID + c * 8;
        float4 lo = *(const float4*)src;
        float4 hi = *(const float4*)(src + 4);
        uint4 pk;
        pk.x = (uint32_t)f2bf(lo.x) | ((uint32_t)f2bf(lo.y) << 16);
        pk.y = (uint32_t)f2bf(lo.z) | ((uint32_t)f2bf(lo.w) << 16);
        pk.z = (uint32_t)f2bf(hi.x) | ((uint32_t)f2bf(hi.y) << 16);
        pk.w = (uint32_t)f2bf(hi.z) | ((uint32_t)f2bf(hi.w) << 16);
        *((uint4*)&sm.w2l[row * 64 + 4 * (c ^ (row & 15))]) = pk;
    }
    // zero histogram
    #pragma unroll
    for (int k = 0; k < 1024 / BLK; ++k) sm.u.hist[tid + k * BLK] = 0;
    if (tid == 0) sm.cnt = 0;
    __syncthreads();

    const float px = pos[3*i], py = pos[3*i+1], pz = pos[3*i+2];

    // ---- distances (exact fp32 mul/add chain to match np) + histogram ----
    for (int j = tid; j < NN; j += BLK) {
        float dx = px - pos[3*j];
        float dy = py - pos[3*j+1];
        float dz = pz - pos[3*j+2];
        float d  = __fadd_rn(__fadd_rn(__fmul_rn(dx,dx), __fmul_rn(dy,dy)), __fmul_rn(dz,dz));
        if (j == i) d = __uint_as_float(0x7f800000u);
        sm.dist[j] = d;
        if (j != i) atomicAdd((int*)&sm.u.hist[__float_as_uint(d) >> 21], 1);
    }
    __syncthreads();

    // ---- find pivot bucket B: first bucket where cumulative count >= KK ----
    {
        const int b0 = tid * 4;
        int h0 = (int)sm.u.hist[b0],   hA = (int)sm.u.hist[b0+1];
        int h2 = (int)sm.u.hist[b0+2], h3 = (int)sm.u.hist[b0+3];
        int s = h0 + hA + h2 + h3;
        int incl = s;
        #pragma unroll
        for (int off = 1; off < 64; off <<= 1) {
            int v = __shfl_up(incl, off, 64);
            if (lane >= off) incl += v;
        }
        if (lane == 63) sm.waveTot[wid] = incl;
        __syncthreads();
        int base = 0;
        for (int w = 0; w < wid; ++w) base += sm.waveTot[w];
        int E = base + incl - s;               // exclusive prefix for this thread
        if (E < KK && E + s >= KK) {           // crossing lies in this thread's 4 buckets
            int cum = E, B = b0 + 3;
            if (cum + h0 >= KK) B = b0;
            else { cum += h0;
                if (cum + hA >= KK) B = b0 + 1;
                else { cum += hA;
                    if (cum + h2 >= KK) B = b0 + 2;
                }
            }
            sm.pivotB = B;
        }
    }
    __syncthreads();

    // ---- compaction: gather all keys with bucket <= B (cand aliases hist) ----
    {
        const int B = sm.pivotB;
        for (int j = tid; j < NN; j += BLK) {
            uint32_t ub = __float_as_uint(sm.dist[j]);   // inf at j==i -> bucket 1020 > B
            if ((int)(ub >> 21) <= B) {
                int slot = atomicAdd(&sm.cnt, 1);
                if (slot < CAP)
                    sm.u.cand[slot] = (((unsigned long long)ub) << 12) | (unsigned)j;
            }
        }
    }
    __syncthreads();

    const int cnt = sm.cnt;   // block-uniform
    if (cnt <= CAP) {
        // ---- rank select: thread m ranks cand[m]; ranks 0..KK-1 are the kNN set ----
        if (tid < cnt) {
            unsigned long long km = sm.u.cand[tid];
            int rank = 0;
            for (int q = 0; q < cnt; ++q)
                rank += (sm.u.cand[q] < km) ? 1 : 0;
            if (rank < KK) sm.recvs[rank] = (int)(km & 0xFFFull);
        }
    } else {
        // ---- fallback (ties overflow; essentially never): exact 32-pass argmin ----
        for (int it = 0; it < KK; ++it) {
            unsigned long long best = ~0ull;
            for (int j = tid; j < NN; j += BLK) {
                unsigned long long key =
                    (((unsigned long long)__float_as_uint(sm.dist[j])) << 12) | (unsigned)j;
                best = best < key ? best : key;
            }
            #pragma unroll
            for (int m = 32; m >= 1; m >>= 1) {
                unsigned long long o = __shfl_xor(best, m, 64);
                best = best < o ? best : o;
            }
            if (lane == 0) sm.redk[wid] = best;
            __syncthreads();
            if (tid == 0) {
                unsigned long long b01 = sm.redk[0] < sm.redk[1] ? sm.redk[0] : sm.redk[1];
                unsigned long long b23 = sm.redk[2] < sm.redk[3] ? sm.redk[2] : sm.redk[3];
                unsigned long long b   = b01 < b23 ? b01 : b23;
                int idx = (int)(b & 0xfffull);
                sm.recvs[it] = idx;
                sm.dist[idx] = __uint_as_float(0x7f800000u);
            }
            __syncthreads();
        }
    }
    __syncthreads();   // recvs visible; dist reads complete (h1s will overwrite)

    // ---- edge MLP: wave w owns edges [8w, 8w+8); each lane 2 neurons x 8 edges ----
    float* h1s = sm.dist + wid * (8 * HID);   // alias
    float a3x = 0.f, a3y = 0.f, a3z = 0.f;
    const int sw = lane & 15;
    const int eb = wid * 8;

    float cdx[8], cdy[8], cdz[8], p0v[8], p1v[8], sq[8];
    #pragma unroll
    for (int e = 0; e < 8; ++e) {
        int r = sm.recvs[eb + e];
        float dx = px - pos[3*r];
        float dy = py - pos[3*r+1];
        float dz = pz - pos[3*r+2];
        cdx[e] = dx; cdy[e] = dy; cdz[e] = dz;
        float rad = __fadd_rn(__fadd_rn(__fmul_rn(dx,dx), __fmul_rn(dy,dy)), __fmul_rn(dz,dz));
        float p0 = rad * w1a0 + tc0;
        float p1 = rad * w1a1 + tc1;
        p0v[e] = p0; p1v[e] = p1;
        sq[e] = p0*p0 + p1*p1;
    }
    #pragma unroll
    for (int m = 32; m >= 1; m >>= 1) {
        #pragma unroll
        for (int e = 0; e < 8; ++e) sq[e] += __shfl_xor(sq[e], m, 64);
    }
    #pragma unroll
    for (int e = 0; e < 8; ++e) {
        float rn = rsqrtf(sq[e] * (1.0f/HID) + 1e-5f);
        h1s[e*HID + n0] = siluf(p0v[e] * rn * g10);
        h1s[e*HID + n1] = siluf(p1v[e] * rn * g11);
    }
    __syncthreads();

    float acc0[8], acc1[8];
    #pragma unroll
    for (int e = 0; e < 8; ++e) { acc0[e] = b20; acc1[e] = b21; }

    for (int c = 0; c < 16; ++c) {
        uint4 wa = *((const uint4*)&sm.w2l[n0*64 + 4*(c ^ sw)]);
        uint4 wb = *((const uint4*)&sm.w2l[n1*64 + 4*(c ^ sw)]);
        float2 a0 = bfp2(wa.x), a1 = bfp2(wa.y), a2 = bfp2(wa.z), a3 = bfp2(wa.w);
        float2 q0 = bfp2(wb.x), q1 = bfp2(wb.y), q2 = bfp2(wb.z), q3 = bfp2(wb.w);
        #pragma unroll
        for (int e = 0; e < 8; ++e) {
            const float4 ha = *((const float4*)&h1s[e*HID + c*8]);
            const float4 hb = *((const float4*)&h1s[e*HID + c*8 + 4]);
            acc0[e] += a0.x*ha.x + a0.y*ha.y + a1.x*ha.z + a1.y*ha.w
                     + a2.x*hb.x + a2.y*hb.y + a3.x*hb.z + a3.y*hb.w;
            acc1[e] += q0.x*ha.x + q0.y*ha.y + q1.x*ha.z + q1.y*ha.w
                     + q2.x*hb.x + q2.y*hb.y + q3.x*hb.z + q3.y*hb.w;
        }
    }

    #pragma unroll
    for (int e = 0; e < 8; ++e) sq[e] = acc0[e]*acc0[e] + acc1[e]*acc1[e];
    #pragma unroll
    for (int m = 32; m >= 1; m >>= 1) {
        #pragma unroll
        for (int e = 0; e < 8; ++e) sq[e] += __shfl_xor(sq[e], m, 64);
    }
    float sv[8];
    #pragma unroll
    for (int e = 0; e < 8; ++e) {
        float rn  = rsqrtf(sq[e] * (1.0f/HID) + 1e-5f);
        float h20 = siluf(acc0[e] * rn * g20);
        float h21 = siluf(acc1[e] * rn * g21);
        sv[e] = h20 * w30 + h21 * w31;
    }
    #pragma unroll
    for (int m = 32; m >= 1; m >>= 1) {
        #pragma unroll
        for (int e = 0; e < 8; ++e) sv[e] += __shfl_xor(sv[e], m, 64);
    }
    #pragma unroll
    for (int e = 0; e < 8; ++e) {
        float s = sv[e] + b3s;
        a3x += cdx[e]*s; a3y += cdy[e]*s; a3z += cdz[e]*s;
    }

    if (lane == 0) { sm.wtr[wid][0] = a3x; sm.wtr[wid][1] = a3y; sm.wtr[wid][2] = a3z; }
    __syncthreads();
    if (tid < 3) {
        float v = pos[3*i + tid] +
                  (sm.wtr[0][tid] + sm.wtr[1][tid] + sm.wtr[2][tid] + sm.wtr[3][tid]) * (1.0f/KK);
        out[3*i + tid] = v;
    }
}

extern "C" void kernel_launch(void* const* d_in, const int* in_sizes, int n_in,
                              void* d_out, int out_size, void* d_ws, size_t ws_size,
                              hipStream_t stream) {
    (void)in_sizes; (void)n_in; (void)out_size; (void)d_ws; (void)ws_size;
    egnn_fused<<<NN, BLK, 0, stream>>>(
        (const float*)d_in[0], (const float*)d_in[1], (const float*)d_in[2],
        (const float*)d_in[3], (const float*)d_in[4], (const float*)d_in[5],
        (const float*)d_in[6], (const float*)d_in[7], (const float*)d_in[8],
        (const float*)d_in[9], (float*)d_out);
}

// Round 5
// 155.786 us; speedup vs baseline: 4.2454x; 1.2683x over previous
//
#include <hip/hip_runtime.h>
#include <stdint.h>

#define NN   4096
#define KK   32
#define HID  128
#define BLK  256
#define CAP  256

typedef unsigned short bf16_t;
typedef __attribute__((ext_vector_type(8))) short bf16x8;
typedef __attribute__((ext_vector_type(4))) float f32x4;

__device__ __forceinline__ bf16_t f2bf(float f) {
    uint32_t u = __float_as_uint(f);
    u = u + 0x7fffu + ((u >> 16) & 1u);   // round-to-nearest-even
    return (bf16_t)(u >> 16);
}
__device__ __forceinline__ float siluf(float x) {
    return x / (1.0f + __expf(-x));
}

struct __align__(16) Smem {
    float dist[NN];            // 16 KB; first 8 KB aliased as h1 bf16 [32][128] (swizzled)
    uint32_t w2l[HID * 64];    // 32 KB; W2 bf16x2, rows of 64 dwords, 16B chunks ^(row&15)
    union {                    // phase-disjoint reuse
        uint32_t hist[1024];
        unsigned long long cand[CAP];
        struct { float ssq[2][KK]; float sedge[2][KK]; } ep;
    } u;
    int recvs[KK];
    float wtr[4][3];
    int waveTot[4];
    unsigned long long redk[4];
    int pivotB;
    int cnt;
};

__global__ __launch_bounds__(BLK) void egnn_fused(
    const float* __restrict__ pos, const float* __restrict__ tptr,
    const float* __restrict__ W1,  const float* __restrict__ b1,
    const float* __restrict__ g1,  const float* __restrict__ W2,
    const float* __restrict__ b2,  const float* __restrict__ g2,
    const float* __restrict__ W3,  const float* __restrict__ b3,
    float* __restrict__ out)
{
    __shared__ Smem sm;
    const int tid  = threadIdx.x;
    const int lane = tid & 63;
    const int wid  = tid >> 6;
    const int i    = blockIdx.x;
    const int l15  = lane & 15, lq = lane >> 4;
    const int mh   = wid & 1,   nh = wid >> 1;   // MFMA tile role

    // ---- layer-1 per-lane constants: neurons n0 = lane, n1 = lane + 64 ----
    const int n0 = lane, n1 = lane + 64;
    const float ts   = tptr[0];
    const float w1a0 = W1[2*n0], w1b0 = W1[2*n0+1];
    const float w1a1 = W1[2*n1], w1b1 = W1[2*n1+1];
    const float tc0  = ts * w1b0 + b1[n0];
    const float tc1  = ts * w1b1 + b1[n1];
    const float g10  = g1[n0], g11 = g1[n1];
    const float b3s  = b3[0];
    // ---- epilogue per-lane constants (MFMA D-layout: n = nh*64 + nt*16 + l15) ----
    float g2v[4], w3v[4], b2v[4];
    #pragma unroll
    for (int nt = 0; nt < 4; ++nt) {
        int n = nh*64 + nt*16 + l15;
        g2v[nt] = g2[n]; w3v[nt] = W3[n]; b2v[nt] = b2[n];
    }

    // ---- stage W2 into LDS (bf16 packed, 16B chunks XOR-swizzled by row&15) ----
    for (int idx = tid; idx < HID * 16; idx += BLK) {
        int row = idx >> 4, c = idx & 15;
        const float* src = W2 + row * HID + c * 8;
        float4 lo = *(const float4*)src;
        float4 hi = *(const float4*)(src + 4);
        uint4 pk;
        pk.x = (uint32_t)f2bf(lo.x) | ((uint32_t)f2bf(lo.y) << 16);
        pk.y = (uint32_t)f2bf(lo.z) | ((uint32_t)f2bf(lo.w) << 16);
        pk.z = (uint32_t)f2bf(hi.x) | ((uint32_t)f2bf(hi.y) << 16);
        pk.w = (uint32_t)f2bf(hi.z) | ((uint32_t)f2bf(hi.w) << 16);
        *((uint4*)&sm.w2l[row * 64 + 4 * (c ^ (row & 15))]) = pk;
    }
    #pragma unroll
    for (int k = 0; k < 1024 / BLK; ++k) sm.u.hist[tid + k * BLK] = 0;
    if (tid == 0) sm.cnt = 0;
    __syncthreads();

    const float px = pos[3*i], py = pos[3*i+1], pz = pos[3*i+2];

    // ---- distances (exact fp32 mul/add chain to match np) + histogram ----
    for (int j = tid; j < NN; j += BLK) {
        float dx = px - pos[3*j];
        float dy = py - pos[3*j+1];
        float dz = pz - pos[3*j+2];
        float d  = __fadd_rn(__fadd_rn(__fmul_rn(dx,dx), __fmul_rn(dy,dy)), __fmul_rn(dz,dz));
        if (j == i) d = __uint_as_float(0x7f800000u);
        sm.dist[j] = d;
        if (j != i) atomicAdd((int*)&sm.u.hist[__float_as_uint(d) >> 21], 1);
    }
    __syncthreads();

    // ---- pivot bucket B: first bucket where cumulative count >= KK ----
    {
        const int b0 = tid * 4;
        int h0 = (int)sm.u.hist[b0],   hA = (int)sm.u.hist[b0+1];
        int h2 = (int)sm.u.hist[b0+2], h3 = (int)sm.u.hist[b0+3];
        int s = h0 + hA + h2 + h3;
        int incl = s;
        #pragma unroll
        for (int off = 1; off < 64; off <<= 1) {
            int v = __shfl_up(incl, off, 64);
            if (lane >= off) incl += v;
        }
        if (lane == 63) sm.waveTot[wid] = incl;
        __syncthreads();
        int base = 0;
        for (int w = 0; w < wid; ++w) base += sm.waveTot[w];
        int E = base + incl - s;
        if (E < KK && E + s >= KK) {
            int cum = E, B = b0 + 3;
            if (cum + h0 >= KK) B = b0;
            else { cum += h0;
                if (cum + hA >= KK) B = b0 + 1;
                else { cum += hA;
                    if (cum + h2 >= KK) B = b0 + 2;
                }
            }
            sm.pivotB = B;
        }
    }
    __syncthreads();

    // ---- compaction: gather keys with bucket <= B (cand aliases hist) ----
    {
        const int B = sm.pivotB;
        for (int j = tid; j < NN; j += BLK) {
            uint32_t ub = __float_as_uint(sm.dist[j]);   // inf at j==i -> bucket > B
            if ((int)(ub >> 21) <= B) {
                int slot = atomicAdd(&sm.cnt, 1);
                if (slot < CAP)
                    sm.u.cand[slot] = (((unsigned long long)ub) << 12) | (unsigned)j;
            }
        }
    }
    __syncthreads();

    const int cnt = sm.cnt;
    if (cnt <= CAP) {
        if (tid < cnt) {
            unsigned long long km = sm.u.cand[tid];
            int rank = 0;
            for (int q = 0; q < cnt; ++q)
                rank += (sm.u.cand[q] < km) ? 1 : 0;
            if (rank < KK) sm.recvs[rank] = (int)(km & 0xFFFull);
        }
    } else {
        // fallback (tie overflow; essentially never): exact 32-pass argmin
        for (int it = 0; it < KK; ++it) {
            unsigned long long best = ~0ull;
            for (int j = tid; j < NN; j += BLK) {
                unsigned long long key =
                    (((unsigned long long)__float_as_uint(sm.dist[j])) << 12) | (unsigned)j;
                best = best < key ? best : key;
            }
            #pragma unroll
            for (int m = 32; m >= 1; m >>= 1) {
                unsigned long long o = __shfl_xor(best, m, 64);
                best = best < o ? best : o;
            }
            if (lane == 0) sm.redk[wid] = best;
            __syncthreads();
            if (tid == 0) {
                unsigned long long b01 = sm.redk[0] < sm.redk[1] ? sm.redk[0] : sm.redk[1];
                unsigned long long b23 = sm.redk[2] < sm.redk[3] ? sm.redk[2] : sm.redk[3];
                unsigned long long b   = b01 < b23 ? b01 : b23;
                int idx = (int)(b & 0xfffull);
                sm.recvs[it] = idx;
                sm.dist[idx] = __uint_as_float(0x7f800000u);
            }
            __syncthreads();
        }
    }
    __syncthreads();   // recvs visible; all dist reads done (h1 will overwrite)

    // ---- geometry + layer 1: wave owns edges [8*wid, 8*wid+8) ----
    const int eb = wid * 8;
    float cdx[8], cdy[8], cdz[8];
    {
        float p0v[8], p1v[8], sq[8];
        #pragma unroll
        for (int e = 0; e < 8; ++e) {
            int r = sm.recvs[eb + e];
            float dx = px - pos[3*r];
            float dy = py - pos[3*r+1];
            float dz = pz - pos[3*r+2];
            cdx[e] = dx; cdy[e] = dy; cdz[e] = dz;
            float rad = __fadd_rn(__fadd_rn(__fmul_rn(dx,dx), __fmul_rn(dy,dy)), __fmul_rn(dz,dz));
            float p0 = rad * w1a0 + tc0;
            float p1 = rad * w1a1 + tc1;
            p0v[e] = p0; p1v[e] = p1;
            sq[e] = p0*p0 + p1*p1;
        }
        #pragma unroll
        for (int m = 32; m >= 1; m >>= 1) {
            #pragma unroll
            for (int e = 0; e < 8; ++e) sq[e] += __shfl_xor(sq[e], m, 64);
        }
        // write h1 as bf16 [32][128], 16B chunks swizzled by ^(edge&15); aliases dist
        ushort* h1w = (ushort*)sm.dist;
        const int c0 = lane >> 3, cl = lane & 7;
        #pragma unroll
        for (int e = 0; e < 8; ++e) {
            float rn = rsqrtf(sq[e] * (1.0f/HID) + 1e-5f);
            int ge = eb + e;
            h1w[ge*HID + ((c0    ) ^ (ge & 15))*8 + cl] = f2bf(siluf(p0v[e] * rn * g10));
            h1w[ge*HID + ((c0 + 8) ^ (ge & 15))*8 + cl] = f2bf(siluf(p1v[e] * rn * g11));
        }
    }
    __syncthreads();

    // ---- layer 2 via MFMA: wave (mh,nh) -> m-tile mh, n-range nh*64..+64 ----
    // A[m=l15][k=lq*8+j] from h1; B[k=lq*8+j][n=l15] = W2[n][k] from w2l; both swizzled ^l15
    f32x4 acc0 = {0.f,0.f,0.f,0.f}, acc1 = acc0, acc2 = acc0, acc3 = acc0;
    {
        const bf16x8* h1v = (const bf16x8*)sm.dist;   // [32][16 chunks]
        const bf16x8* w2v = (const bf16x8*)sm.w2l;    // [128][16 chunks]
        const int m = mh*16 + l15;
        const int nrow0 = (nh*64 +      l15) * 16;
        const int nrow1 = (nh*64 + 16 + l15) * 16;
        const int nrow2 = (nh*64 + 32 + l15) * 16;
        const int nrow3 = (nh*64 + 48 + l15) * 16;
        #pragma unroll
        for (int kk = 0; kk < 4; ++kk) {
            const int q = (kk*4 + lq) ^ l15;
            bf16x8 af = h1v[m*16 + q];
            acc0 = __builtin_amdgcn_mfma_f32_16x16x32_bf16(af, w2v[nrow0 + q], acc0, 0, 0, 0);
            acc1 = __builtin_amdgcn_mfma_f32_16x16x32_bf16(af, w2v[nrow1 + q], acc1, 0, 0, 0);
            acc2 = __builtin_amdgcn_mfma_f32_16x16x32_bf16(af, w2v[nrow2 + q], acc2, 0, 0, 0);
            acc3 = __builtin_amdgcn_mfma_f32_16x16x32_bf16(af, w2v[nrow3 + q], acc3, 0, 0, 0);
        }
    }

    // z[nt][r] = pre-norm layer-2 output for (edge mh*16+lq*4+r, neuron nh*64+nt*16+l15)
    float z[4][4];
    #pragma unroll
    for (int r = 0; r < 4; ++r) {
        z[0][r] = acc0[r] + b2v[0];
        z[1][r] = acc1[r] + b2v[1];
        z[2][r] = acc2[r] + b2v[2];
        z[3][r] = acc3[r] + b2v[3];
    }

    // sum of squares over this wave's 64 neurons, per edge (quad-local reduce)
    float ss[4];
    #pragma unroll
    for (int r = 0; r < 4; ++r)
        ss[r] = z[0][r]*z[0][r] + z[1][r]*z[1][r] + z[2][r]*z[2][r] + z[3][r]*z[3][r];
    #pragma unroll
    for (int m = 8; m >= 1; m >>= 1) {
        #pragma unroll
        for (int r = 0; r < 4; ++r) ss[r] += __shfl_xor(ss[r], m, 64);
    }
    if (l15 == 0) {
        #pragma unroll
        for (int r = 0; r < 4; ++r) sm.u.ep.ssq[nh][mh*16 + lq*4 + r] = ss[r];
    }
    __syncthreads();

    // h2 = silu(rmsnorm(z)*g2); per-edge partial of h2 . W3 over this wave's neurons
    float sp[4];
    #pragma unroll
    for (int r = 0; r < 4; ++r) {
        int e = mh*16 + lq*4 + r;
        float rn = rsqrtf((sm.u.ep.ssq[0][e] + sm.u.ep.ssq[1][e]) * (1.0f/HID) + 1e-5f);
        float v = siluf(z[0][r] * rn * g2v[0]) * w3v[0]
                + siluf(z[1][r] * rn * g2v[1]) * w3v[1]
                + siluf(z[2][r] * rn * g2v[2]) * w3v[2]
                + siluf(z[3][r] * rn * g2v[3]) * w3v[3];
        sp[r] = v;
    }
    #pragma unroll
    for (int m = 8; m >= 1; m >>= 1) {
        #pragma unroll
        for (int r = 0; r < 4; ++r) sp[r] += __shfl_xor(sp[r], m, 64);
    }
    if (l15 == 0) {
        #pragma unroll
        for (int r = 0; r < 4; ++r) sm.u.ep.sedge[nh][mh*16 + lq*4 + r] = sp[r];
    }
    __syncthreads();

    // ---- final: edge scalar s[e] -> message accumulate (geometry wave owns cd) ----
    float a3x = 0.f, a3y = 0.f, a3z = 0.f;
    #pragma unroll
    for (int e = 0; e < 8; ++e) {
        int ge = eb + e;
        float s = sm.u.ep.sedge[0][ge] + sm.u.ep.sedge[1][ge] + b3s;
        a3x += cdx[e]*s; a3y += cdy[e]*s; a3z += cdz[e]*s;
    }
    if (lane == 0) { sm.wtr[wid][0] = a3x; sm.wtr[wid][1] = a3y; sm.wtr[wid][2] = a3z; }
    __syncthreads();
    if (tid < 3) {
        float v = pos[3*i + tid] +
                  (sm.wtr[0][tid] + sm.wtr[1][tid] + sm.wtr[2][tid] + sm.wtr[3][tid]) * (1.0f/KK);
        out[3*i + tid] = v;
    }
}

extern "C" void kernel_launch(void* const* d_in, const int* in_sizes, int n_in,
                              void* d_out, int out_size, void* d_ws, size_t ws_size,
                              hipStream_t stream) {
    (void)in_sizes; (void)n_in; (void)out_size; (void)d_ws; (void)ws_size;
    egnn_fused<<<NN, BLK, 0, stream>>>(
        (const float*)d_in[0], (const float*)d_in[1], (const float*)d_in[2],
        (const float*)d_in[3], (const float*)d_in[4], (const float*)d_in[5],
        (const float*)d_in[6], (const float*)d_in[7], (const float*)d_in[8],
        (const float*)d_in[9], (float*)d_out);
}

// Round 6
// 135.521 us; speedup vs baseline: 4.8803x; 1.1495x over previous
//
#include <hip/hip_runtime.h>
#include <stdint.h>

#define NN   4096
#define KK   32
#define HID  128
#define BLK  256
#define CAP  256

typedef unsigned short bf16_t;
typedef __attribute__((ext_vector_type(8))) short bf16x8;
typedef __attribute__((ext_vector_type(4))) float f32x4;

__device__ __forceinline__ bf16_t f2bf(float f) {
    uint32_t u = __float_as_uint(f);
    u = u + 0x7fffu + ((u >> 16) & 1u);   // round-to-nearest-even
    return (bf16_t)(u >> 16);
}
__device__ __forceinline__ float siluf(float x) {
    return x / (1.0f + __expf(-x));
}

// ---- prepack: W2 fp32 -> bf16, laid out in MFMA B-fragment order ----
// chunk c (0..2047): frag f=c>>6 (= (nh*4+nt)*4+kk), lane=c&63.
// contents: W2[row = nh*64+nt*16+(lane&15)][k = kk*32+(lane>>4)*8 .. +8]
__global__ __launch_bounds__(BLK) void prepack_w2(
    const float* __restrict__ W2, uint4* __restrict__ w2b)
{
    int c  = blockIdx.x * BLK + threadIdx.x;
    int f  = c >> 6, ln = c & 63;
    int nh = f >> 4, nt = (f >> 2) & 3, kk = f & 3;
    int row = nh*64 + nt*16 + (ln & 15);
    int k0  = kk*32 + (ln >> 4) * 8;
    const float* s = W2 + row * HID + k0;
    float4 lo = *(const float4*)s;
    float4 hi = *(const float4*)(s + 4);
    uint4 pk;
    pk.x = (uint32_t)f2bf(lo.x) | ((uint32_t)f2bf(lo.y) << 16);
    pk.y = (uint32_t)f2bf(lo.z) | ((uint32_t)f2bf(lo.w) << 16);
    pk.z = (uint32_t)f2bf(hi.x) | ((uint32_t)f2bf(hi.y) << 16);
    pk.w = (uint32_t)f2bf(hi.z) | ((uint32_t)f2bf(hi.w) << 16);
    w2b[c] = pk;
}

template<bool WS>
struct __align__(16) Sm {
    union __align__(16) {                 // phase-disjoint reuse
        uint32_t hist[1024];              // 4 KB  (dist phase)
        unsigned long long cand[CAP];     // 2 KB  (selection)
        ushort h1[KK * HID];              // 8 KB  (MLP: bf16, 16B chunks ^(edge&15))
    } u;
    uint32_t w2l[WS ? 4 : HID * 64];      // only the no-workspace fallback stages W2
    float ssq[2][KK];
    float sedge[2][KK];
    int recvs[KK];
    float wtr[4][3];
    int waveTot[4];
    unsigned long long redk[4];
    int pivotB;
    int cnt;
    int chosen;
};

template<bool WS>
__global__ __launch_bounds__(BLK) void egnn_main(
    const float* __restrict__ pos, const float* __restrict__ tptr,
    const float* __restrict__ W1,  const float* __restrict__ b1,
    const float* __restrict__ g1,  const float* __restrict__ W2,
    const float* __restrict__ b2,  const float* __restrict__ g2,
    const float* __restrict__ W3,  const float* __restrict__ b3,
    const uint4* __restrict__ w2b, float* __restrict__ out)
{
    __shared__ Sm<WS> sm;
    const int tid  = threadIdx.x;
    const int lane = tid & 63;
    const int wid  = tid >> 6;
    const int i    = blockIdx.x;
    const int l15  = lane & 15, lq = lane >> 4;
    const int mh   = wid & 1,   nh = wid >> 1;   // MFMA tile role

    // ---- layer-1 per-lane constants: neurons n0 = lane, n1 = lane + 64 ----
    const int n0 = lane, n1 = lane + 64;
    const float ts   = tptr[0];
    const float w1a0 = W1[2*n0], w1b0 = W1[2*n0+1];
    const float w1a1 = W1[2*n1], w1b1 = W1[2*n1+1];
    const float tc0  = ts * w1b0 + b1[n0];
    const float tc1  = ts * w1b1 + b1[n1];
    const float g10  = g1[n0], g11 = g1[n1];
    const float b3s  = b3[0];
    // ---- epilogue per-lane constants (MFMA D-layout: n = nh*64 + nt*16 + l15) ----
    float g2v[4], w3v[4], b2v[4];
    #pragma unroll
    for (int nt = 0; nt < 4; ++nt) {
        int n = nh*64 + nt*16 + l15;
        g2v[nt] = g2[n]; w3v[nt] = W3[n]; b2v[nt] = b2[n];
    }

    if constexpr (!WS) {
        // fallback: stage W2 into LDS (bf16, 16B chunks XOR-swizzled by row&15)
        for (int idx = tid; idx < HID * 16; idx += BLK) {
            int row = idx >> 4, c = idx & 15;
            const float* src = W2 + row * HID + c * 8;
            float4 lo = *(const float4*)src;
            float4 hi = *(const float4*)(src + 4);
            uint4 pk;
            pk.x = (uint32_t)f2bf(lo.x) | ((uint32_t)f2bf(lo.y) << 16);
            pk.y = (uint32_t)f2bf(lo.z) | ((uint32_t)f2bf(lo.w) << 16);
            pk.z = (uint32_t)f2bf(hi.x) | ((uint32_t)f2bf(hi.y) << 16);
            pk.w = (uint32_t)f2bf(hi.z) | ((uint32_t)f2bf(hi.w) << 16);
            *((uint4*)&sm.w2l[row * 64 + 4 * (c ^ (row & 15))]) = pk;
        }
    }
    #pragma unroll
    for (int k = 0; k < 1024 / BLK; ++k) sm.u.hist[tid + k * BLK] = 0;
    if (tid == 0) sm.cnt = 0;
    __syncthreads();

    const float px = pos[3*i], py = pos[3*i+1], pz = pos[3*i+2];

    // ---- distances into REGISTERS (exact fp32 chain) + LDS histogram ----
    // thread covers j = 1024*g + 4*tid + c  (g<4, c<4); pos read as 3x float4
    float dreg[4][4];
    {
        const float4* p4 = (const float4*)pos;
        #pragma unroll
        for (int g = 0; g < 4; ++g) {
            float4 f0 = p4[768*g + 3*tid];
            float4 f1 = p4[768*g + 3*tid + 1];
            float4 f2 = p4[768*g + 3*tid + 2];
            float jx[4] = {f0.x, f0.w, f1.z, f2.y};
            float jy[4] = {f0.y, f1.x, f1.w, f2.z};
            float jz[4] = {f0.z, f1.y, f2.x, f2.w};
            #pragma unroll
            for (int c = 0; c < 4; ++c) {
                int j = 1024*g + 4*tid + c;
                float dx = px - jx[c];
                float dy = py - jy[c];
                float dz = pz - jz[c];
                float d = __fadd_rn(__fadd_rn(__fmul_rn(dx,dx), __fmul_rn(dy,dy)),
                                    __fmul_rn(dz,dz));
                if (j == i) d = __uint_as_float(0x7f800000u);
                dreg[g][c] = d;
                if (j != i) atomicAdd((int*)&sm.u.hist[__float_as_uint(d) >> 21], 1);
            }
        }
    }
    __syncthreads();

    // ---- pivot bucket B: first bucket where cumulative count >= KK ----
    {
        const int b0 = tid * 4;
        int h0 = (int)sm.u.hist[b0],   hA = (int)sm.u.hist[b0+1];
        int h2 = (int)sm.u.hist[b0+2], h3 = (int)sm.u.hist[b0+3];
        int s = h0 + hA + h2 + h3;
        int incl = s;
        #pragma unroll
        for (int off = 1; off < 64; off <<= 1) {
            int v = __shfl_up(incl, off, 64);
            if (lane >= off) incl += v;
        }
        if (lane == 63) sm.waveTot[wid] = incl;
        __syncthreads();
        int base = 0;
        for (int w = 0; w < wid; ++w) base += sm.waveTot[w];
        int E = base + incl - s;
        if (E < KK && E + s >= KK) {
            int cum = E, B = b0 + 3;
            if (cum + h0 >= KK) B = b0;
            else { cum += h0;
                if (cum + hA >= KK) B = b0 + 1;
                else { cum += hA;
                    if (cum + h2 >= KK) B = b0 + 2;
                }
            }
            sm.pivotB = B;
        }
    }
    __syncthreads();

    // ---- compaction from registers: keys with bucket <= B (cand aliases hist) ----
    {
        const int B = sm.pivotB;
        #pragma unroll
        for (int g = 0; g < 4; ++g) {
            #pragma unroll
            for (int c = 0; c < 4; ++c) {
                uint32_t ub = __float_as_uint(dreg[g][c]);   // inf at j==i -> bucket > B
                if ((int)(ub >> 21) <= B) {
                    int slot = atomicAdd(&sm.cnt, 1);
                    if (slot < CAP)
                        sm.u.cand[slot] = (((unsigned long long)ub) << 12)
                                        | (unsigned)(1024*g + 4*tid + c);
                }
            }
        }
    }
    __syncthreads();

    const int cnt = sm.cnt;
    if (cnt <= CAP) {
        if (tid < cnt) {
            unsigned long long km = sm.u.cand[tid];
            int rank = 0;
            for (int q = 0; q < cnt; ++q)
                rank += (sm.u.cand[q] < km) ? 1 : 0;
            if (rank < KK) sm.recvs[rank] = (int)(km & 0xFFFull);
        }
    } else {
        // fallback (tie overflow; essentially never): exact 32-pass argmin over regs
        for (int it = 0; it < KK; ++it) {
            unsigned long long best = ~0ull;
            #pragma unroll
            for (int g = 0; g < 4; ++g)
                #pragma unroll
                for (int c = 0; c < 4; ++c) {
                    unsigned long long key =
                        (((unsigned long long)__float_as_uint(dreg[g][c])) << 12)
                        | (unsigned)(1024*g + 4*tid + c);
                    best = best < key ? best : key;
                }
            #pragma unroll
            for (int m = 32; m >= 1; m >>= 1) {
                unsigned long long o = __shfl_xor(best, m, 64);
                best = best < o ? best : o;
            }
            if (lane == 0) sm.redk[wid] = best;
            __syncthreads();
            if (tid == 0) {
                unsigned long long b01 = sm.redk[0] < sm.redk[1] ? sm.redk[0] : sm.redk[1];
                unsigned long long b23 = sm.redk[2] < sm.redk[3] ? sm.redk[2] : sm.redk[3];
                unsigned long long b   = b01 < b23 ? b01 : b23;
                int j = (int)(b & 0xfffull);
                sm.recvs[it] = j;
                sm.chosen = j;
            }
            __syncthreads();
            int j = sm.chosen;
            if (((j & 1023) >> 2) == tid)
                dreg[j >> 10][j & 3] = __uint_as_float(0x7f800000u);
        }
    }
    __syncthreads();   // recvs visible; hist/cand dead (h1 will overwrite union)

    // ---- geometry + layer 1: wave owns edges [8*wid, 8*wid+8) ----
    const int eb = wid * 8;
    float cdx[8], cdy[8], cdz[8];
    {
        float p0v[8], p1v[8], sq[8];
        #pragma unroll
        for (int e = 0; e < 8; ++e) {
            int r = sm.recvs[eb + e];
            float dx = px - pos[3*r];
            float dy = py - pos[3*r+1];
            float dz = pz - pos[3*r+2];
            cdx[e] = dx; cdy[e] = dy; cdz[e] = dz;
            float rad = __fadd_rn(__fadd_rn(__fmul_rn(dx,dx), __fmul_rn(dy,dy)),
                                  __fmul_rn(dz,dz));
            float p0 = rad * w1a0 + tc0;
            float p1 = rad * w1a1 + tc1;
            p0v[e] = p0; p1v[e] = p1;
            sq[e] = p0*p0 + p1*p1;
        }
        #pragma unroll
        for (int m = 32; m >= 1; m >>= 1) {
            #pragma unroll
            for (int e = 0; e < 8; ++e) sq[e] += __shfl_xor(sq[e], m, 64);
        }
        // h1 bf16 [32][128], 16B chunks swizzled by ^(edge&15)
        ushort* h1w = sm.u.h1;
        const int c0 = lane >> 3, cl = lane & 7;
        #pragma unroll
        for (int e = 0; e < 8; ++e) {
            float rn = rsqrtf(sq[e] * (1.0f/HID) + 1e-5f);
            int ge = eb + e;
            h1w[ge*HID + ((c0    ) ^ (ge & 15))*8 + cl] = f2bf(siluf(p0v[e] * rn * g10));
            h1w[ge*HID + ((c0 + 8) ^ (ge & 15))*8 + cl] = f2bf(siluf(p1v[e] * rn * g11));
        }
    }
    __syncthreads();

    // ---- layer 2 via MFMA: A from LDS h1; B from global (WS) or LDS (fallback) ----
    f32x4 acc0 = {0.f,0.f,0.f,0.f}, acc1 = acc0, acc2 = acc0, acc3 = acc0;
    {
        const bf16x8* h1v = (const bf16x8*)sm.u.h1;   // [32][16 chunks]
        const int m = mh*16 + l15;
        if constexpr (WS) {
            const bf16x8* bv = (const bf16x8*)w2b;
            #pragma unroll
            for (int kk = 0; kk < 4; ++kk) {
                bf16x8 af = h1v[m*16 + ((kk*4 + lq) ^ l15)];
                acc0 = __builtin_amdgcn_mfma_f32_16x16x32_bf16(
                           af, bv[((nh*4+0)*4 + kk)*64 + lane], acc0, 0, 0, 0);
                acc1 = __builtin_amdgcn_mfma_f32_16x16x32_bf16(
                           af, bv[((nh*4+1)*4 + kk)*64 + lane], acc1, 0, 0, 0);
                acc2 = __builtin_amdgcn_mfma_f32_16x16x32_bf16(
                           af, bv[((nh*4+2)*4 + kk)*64 + lane], acc2, 0, 0, 0);
                acc3 = __builtin_amdgcn_mfma_f32_16x16x32_bf16(
                           af, bv[((nh*4+3)*4 + kk)*64 + lane], acc3, 0, 0, 0);
            }
        } else {
            const bf16x8* w2v = (const bf16x8*)sm.w2l;    // [128][16 chunks]
            const int nrow0 = (nh*64 +      l15) * 16;
            const int nrow1 = (nh*64 + 16 + l15) * 16;
            const int nrow2 = (nh*64 + 32 + l15) * 16;
            const int nrow3 = (nh*64 + 48 + l15) * 16;
            #pragma unroll
            for (int kk = 0; kk < 4; ++kk) {
                const int q = (kk*4 + lq) ^ l15;
                bf16x8 af = h1v[m*16 + q];
                acc0 = __builtin_amdgcn_mfma_f32_16x16x32_bf16(af, w2v[nrow0 + q], acc0, 0, 0, 0);
                acc1 = __builtin_amdgcn_mfma_f32_16x16x32_bf16(af, w2v[nrow1 + q], acc1, 0, 0, 0);
                acc2 = __builtin_amdgcn_mfma_f32_16x16x32_bf16(af, w2v[nrow2 + q], acc2, 0, 0, 0);
                acc3 = __builtin_amdgcn_mfma_f32_16x16x32_bf16(af, w2v[nrow3 + q], acc3, 0, 0, 0);
            }
        }
    }

    // z[nt][r]: pre-norm layer-2 out for (edge mh*16+lq*4+r, neuron nh*64+nt*16+l15)
    float z[4][4];
    #pragma unroll
    for (int r = 0; r < 4; ++r) {
        z[0][r] = acc0[r] + b2v[0];
        z[1][r] = acc1[r] + b2v[1];
        z[2][r] = acc2[r] + b2v[2];
        z[3][r] = acc3[r] + b2v[3];
    }

    float ss[4];
    #pragma unroll
    for (int r = 0; r < 4; ++r)
        ss[r] = z[0][r]*z[0][r] + z[1][r]*z[1][r] + z[2][r]*z[2][r] + z[3][r]*z[3][r];
    #pragma unroll
    for (int m = 8; m >= 1; m >>= 1) {
        #pragma unroll
        for (int r = 0; r < 4; ++r) ss[r] += __shfl_xor(ss[r], m, 64);
    }
    if (l15 == 0) {
        #pragma unroll
        for (int r = 0; r < 4; ++r) sm.ssq[nh][mh*16 + lq*4 + r] = ss[r];
    }
    __syncthreads();

    float sp[4];
    #pragma unroll
    for (int r = 0; r < 4; ++r) {
        int e = mh*16 + lq*4 + r;
        float rn = rsqrtf((sm.ssq[0][e] + sm.ssq[1][e]) * (1.0f/HID) + 1e-5f);
        sp[r] = siluf(z[0][r] * rn * g2v[0]) * w3v[0]
              + siluf(z[1][r] * rn * g2v[1]) * w3v[1]
              + siluf(z[2][r] * rn * g2v[2]) * w3v[2]
              + siluf(z[3][r] * rn * g2v[3]) * w3v[3];
    }
    #pragma unroll
    for (int m = 8; m >= 1; m >>= 1) {
        #pragma unroll
        for (int r = 0; r < 4; ++r) sp[r] += __shfl_xor(sp[r], m, 64);
    }
    if (l15 == 0) {
        #pragma unroll
        for (int r = 0; r < 4; ++r) sm.sedge[nh][mh*16 + lq*4 + r] = sp[r];
    }
    __syncthreads();

    // ---- final: edge scalar -> message accumulate (geometry wave owns cd) ----
    float a3x = 0.f, a3y = 0.f, a3z = 0.f;
    #pragma unroll
    for (int e = 0; e < 8; ++e) {
        int ge = eb + e;
        float s = sm.sedge[0][ge] + sm.sedge[1][ge] + b3s;
        a3x += cdx[e]*s; a3y += cdy[e]*s; a3z += cdz[e]*s;
    }
    if (lane == 0) { sm.wtr[wid][0] = a3x; sm.wtr[wid][1] = a3y; sm.wtr[wid][2] = a3z; }
    __syncthreads();
    if (tid < 3) {
        float v = pos[3*i + tid] +
                  (sm.wtr[0][tid] + sm.wtr[1][tid] + sm.wtr[2][tid] + sm.wtr[3][tid]) * (1.0f/KK);
        out[3*i + tid] = v;
    }
}

extern "C" void kernel_launch(void* const* d_in, const int* in_sizes, int n_in,
                              void* d_out, int out_size, void* d_ws, size_t ws_size,
                              hipStream_t stream) {
    (void)in_sizes; (void)n_in; (void)out_size;
    const float* pos = (const float*)d_in[0];
    const float* t   = (const float*)d_in[1];
    const float* W1  = (const float*)d_in[2];
    const float* b1  = (const float*)d_in[3];
    const float* g1  = (const float*)d_in[4];
    const float* W2  = (const float*)d_in[5];
    const float* b2  = (const float*)d_in[6];
    const float* g2  = (const float*)d_in[7];
    const float* W3  = (const float*)d_in[8];
    const float* b3  = (const float*)d_in[9];
    float* out = (float*)d_out;

    if (d_ws != nullptr && ws_size >= 32768) {
        prepack_w2<<<8, BLK, 0, stream>>>(W2, (uint4*)d_ws);
        egnn_main<true><<<NN, BLK, 0, stream>>>(
            pos, t, W1, b1, g1, W2, b2, g2, W3, b3, (const uint4*)d_ws, out);
    } else {
        egnn_main<false><<<NN, BLK, 0, stream>>>(
            pos, t, W1, b1, g1, W2, b2, g2, W3, b3, nullptr, out);
    }
}